// Round 21
// baseline (5023.523 us; speedup 1.0000x reference)
//
#include <hip/hip_runtime.h>
#include <stdint.h>

#define N 2048
#define BATCH 8
#define NROWS (BATCH * N)   // 16384
#define K64 64              // stored sorted candidates per row
#define LE 16               // LDS list entries per row in DA (ranks 0..15)
#define EXQ 2048            // event ring (>= max pushes)
#define INV 0xFFFFFFFFu

typedef unsigned long long u64;
typedef unsigned u32;
typedef unsigned short u16;

#define DEADK 0xFFFFFFFFFFFFFFFFull

// ---------------- DPP wave64 reductions -----------------------------------
__device__ __forceinline__ unsigned wave_umin_bcast(unsigned x) {
#define DPP_MIN(ctrl)                                                          \
  {                                                                            \
    unsigned t = (unsigned)__builtin_amdgcn_update_dpp((int)x, (int)x, ctrl,   \
                                                       0xf, 0xf, false);       \
    x = t < x ? t : x;                                                         \
  }
  DPP_MIN(0x111) DPP_MIN(0x112) DPP_MIN(0x114) DPP_MIN(0x118)
  DPP_MIN(0x142) DPP_MIN(0x143)
#undef DPP_MIN
  return (unsigned)__builtin_amdgcn_readlane((int)x, 63);
}

__device__ __forceinline__ unsigned wave_umax_bcast(unsigned x) {
#define DPP_MAX(ctrl)                                                          \
  {                                                                            \
    unsigned t = (unsigned)__builtin_amdgcn_update_dpp((int)x, (int)x, ctrl,   \
                                                       0xf, 0xf, false);       \
    x = t > x ? t : x;                                                         \
  }
  DPP_MAX(0x111) DPP_MAX(0x112) DPP_MAX(0x114) DPP_MAX(0x118)
  DPP_MAX(0x142) DPP_MAX(0x143)
#undef DPP_MAX
  return (unsigned)__builtin_amdgcn_readlane((int)x, 63);
}

#define DPP64_MIN(x, ctrl)                                                     \
  {                                                                            \
    u32 lo_ = (u32)(x), hi_ = (u32)((x) >> 32);                                \
    u32 tlo_ = (u32)__builtin_amdgcn_update_dpp((int)lo_, (int)lo_, (ctrl),    \
                                                0xf, 0xf, false);              \
    u32 thi_ = (u32)__builtin_amdgcn_update_dpp((int)hi_, (int)hi_, (ctrl),    \
                                                0xf, 0xf, false);              \
    u64 t_ = ((u64)thi_ << 32) | tlo_;                                         \
    x = t_ < x ? t_ : x;                                                       \
  }

__device__ __forceinline__ u64 wave_min64_l63(u64 x) {
  DPP64_MIN(x, 0x111) DPP64_MIN(x, 0x112) DPP64_MIN(x, 0x114)
  DPP64_MIN(x, 0x118) DPP64_MIN(x, 0x142) DPP64_MIN(x, 0x143)
  return x;
}

// Exact-order distance: ((dx*dx + dy*dy) + dz*dz), no FMA contraction, sqrtf.
#define DIST(qx, qy, qz, TX, TY, TZ, j, dout)                                  \
  do {                                                                         \
    _Pragma("clang fp contract(off)")                                          \
    float dx_ = (qx) - (TX)[j];                                                \
    float dy_ = (qy) - (TY)[j];                                                \
    float dz_ = (qz) - (TZ)[j];                                                \
    float s_ = dx_ * dx_ + dy_ * dy_ + dz_ * dz_;                              \
    dout = sqrtf(s_);                                                          \
  } while (0)

// ---------------- Phase 1 (FUSED): tau-shortlist -> sorted top-64 ----------
// (verified R19/R20, absmax 0.0)
__global__ __launch_bounds__(256, 1)
void emd_shortsort_kernel(const float* __restrict__ pred,
                          const float* __restrict__ target,
                          u64* __restrict__ keys) {
    __shared__ float tx[N], ty[N], tz[N];        // 24KB
    __shared__ u64 cand[4 * 256];                // 8KB per-wave scratch

    const int b  = blockIdx.x >> 9;
    const int r0 = (blockIdx.x & 511) << 2;
    const float* tb = target + (size_t)b * N * 3;

    for (int idx = threadIdx.x; idx < 3 * N; idx += 256) {
        float v = tb[idx];
        int n = idx / 3, c = idx - 3 * n;
        if (c == 0) tx[n] = v; else if (c == 1) ty[n] = v; else tz[n] = v;
    }
    __syncthreads();

    const int wid = threadIdx.x >> 6, lane = threadIdx.x & 63;
    const int i = r0 + wid;
    const size_t row = (size_t)b * N + i;
    const float* pb = pred + row * 3;
    const float qx = pb[0], qy = pb[1], qz = pb[2];

    float d[32];
    float m = 3.4e38f;
    #pragma unroll
    for (int c = 0; c < 32; ++c) {
        const int j = (c << 6) + lane;
        float dd;
        DIST(qx, qy, qz, tx, ty, tz, j, dd);
        d[c] = dd;
        m = fminf(m, dd);
    }

    unsigned mb = __float_as_uint(m);
    {   // pair-min (xor1 quad_perm): tau = max of 32 min-of-64 -> E[cnt]~130
        unsigned t = (unsigned)__builtin_amdgcn_update_dpp((int)mb, (int)mb,
                                                           0x0B1, 0xf, 0xf, false);
        mb = t < mb ? t : mb;
    }
    const unsigned tau = wave_umax_bcast(mb);
    const float tauf = __uint_as_float(tau);

    u64* cw = cand + wid * 256;
    unsigned base = 0;
    #pragma unroll
    for (int c = 0; c < 32; ++c) {
        const bool p = d[c] <= tauf;
        const u64 bm = __ballot(p);
        if (p) {
            unsigned off = base + (unsigned)__popcll(bm & ((1ull << lane) - 1ull));
            if (off < 256u)
                cw[off] = ((u64)__float_as_uint(d[c]) << 32) |
                          (unsigned)((c << 6) + lane);
        }
        base += (unsigned)__popcll(bm);
    }
    const u32 lim = (base > 256u) ? 0u : base;   // overflow -> all DEADK

    u64 k0 = ((u32)lane       < lim) ? cw[lane      ] : DEADK;
    u64 k1 = ((u32)lane + 64  < lim) ? cw[lane + 64 ] : DEADK;
    u64 k2 = ((u32)lane + 128 < lim) ? cw[lane + 128] : DEADK;
    u64 k3 = ((u32)lane + 192 < lim) ? cw[lane + 192] : DEADK;

#define CSWAP(a, b)                                                            \
  { u64 mn_ = (a) < (b) ? (a) : (b); u64 mx_ = (a) < (b) ? (b) : (a);          \
    (a) = mn_; (b) = mx_; }
    CSWAP(k0, k1) CSWAP(k2, k3) CSWAP(k0, k2) CSWAP(k1, k3) CSWAP(k1, k2)
#undef CSWAP

    u64 mykey = DEADK;
    for (int it = 0; it < K64; ++it) {
        u64 wm = wave_min64_l63(k0);
        u32 wlo = (u32)__builtin_amdgcn_readlane((int)(u32)wm, 63);
        u32 whi = (u32)__builtin_amdgcn_readlane((int)(u32)(wm >> 32), 63);
        if (whi == 0xFFFFFFFFu) break;
        const u64 wkey = ((u64)whi << 32) | wlo;
        mykey = (lane == it) ? wkey : mykey;
        const bool eq = (k0 == wkey);
        k0 = eq ? k1 : k0; k1 = eq ? k2 : k1; k2 = eq ? k3 : k2;
        k3 = eq ? DEADK : k3;
    }
    keys[row * (size_t)K64 + lane] = mykey;
}

// 8-wide batched segment probe (R20): one 16B LDS read + 8 pipelined holder
// reads; builds alive (h>r) / dead (0xFFFF) masks. Named scalars (rule #20).
#define SEG_PROBE(LISTBASE, SEG, R)                                            \
    const uint4 w_ = *(const uint4*)&(LISTBASE)[(SEG)];                        \
    const u32 t0_ = w_.x & 0xFFFFu, t1_ = w_.x >> 16;                          \
    const u32 t2_ = w_.y & 0xFFFFu, t3_ = w_.y >> 16;                          \
    const u32 t4_ = w_.z & 0xFFFFu, t5_ = w_.z >> 16;                          \
    const u32 t6_ = w_.w & 0xFFFFu, t7_ = w_.w >> 16;                          \
    const u32 h0_ = holder[t0_ & (N - 1)], h1_ = holder[t1_ & (N - 1)];        \
    const u32 h2_ = holder[t2_ & (N - 1)], h3_ = holder[t3_ & (N - 1)];        \
    const u32 h4_ = holder[t4_ & (N - 1)], h5_ = holder[t5_ & (N - 1)];        \
    const u32 h6_ = holder[t6_ & (N - 1)], h7_ = holder[t7_ & (N - 1)];        \
    u32 am_ = 0, dm_ = 0;                                                      \
    if (t0_ == 0xFFFFu) dm_ |= 1u;   else if (h0_ > (R)) am_ |= 1u;            \
    if (t1_ == 0xFFFFu) dm_ |= 2u;   else if (h1_ > (R)) am_ |= 2u;            \
    if (t2_ == 0xFFFFu) dm_ |= 4u;   else if (h2_ > (R)) am_ |= 4u;            \
    if (t3_ == 0xFFFFu) dm_ |= 8u;   else if (h3_ > (R)) am_ |= 8u;            \
    if (t4_ == 0xFFFFu) dm_ |= 16u;  else if (h4_ > (R)) am_ |= 16u;           \
    if (t5_ == 0xFFFFu) dm_ |= 32u;  else if (h5_ > (R)) am_ |= 32u;           \
    if (t6_ == 0xFFFFu) dm_ |= 64u;  else if (h6_ > (R)) am_ |= 64u;           \
    if (t7_ == 0xFFFFu) dm_ |= 128u; else if (h7_ > (R)) am_ |= 128u;

#define SEG_TARGET(E)                                                          \
    ((E) < 2 ? ((E) & 1 ? t1_ : t0_)                                           \
             : (E) < 4 ? ((E) & 1 ? t3_ : t2_)                                 \
                       : (E) < 6 ? ((E) & 1 ? t5_ : t4_)                       \
                                 : ((E) & 1 ? t7_ : t6_))

#define SEG_HOLD(E)                                                            \
    ((E) < 2 ? ((E) & 1 ? h1_ : h0_)                                           \
             : (E) < 4 ? ((E) & 1 ? h3_ : h2_)                                 \
                       : (E) < 6 ? ((E) & 1 ? h5_ : h4_)                       \
                                 : ((E) & 1 ? h7_ : h6_))

// ---------------- Phase 2: da10 — single-wave ATOMIC-FREE stage 2 ----------
// THEOREM (HW-validated R9-R20, absmax 0.0): greedy row-order matching ==
// unique stable matching == row-proposing DA under ANY proposal order; total
// rank-advances are execution-order-invariant. R20 falsified probe-cost as
// the wall (batched probes: no change) -> the stage-2 critical path is
// atomicMin-return + broadcast + retry overhead per chain step. da10: stage 2
// runs on ONE wave that exclusively owns holder[] after the barrier -- plain
// ds_write updates (no atomic-return stall), exact holder reads (retries
// structurally impossible), single-pass scans. 8 blocks still parallel.
__global__ __launch_bounds__(1024, 1)
void emd_da10_kernel(const float* __restrict__ pred,
                     const float* __restrict__ target,
                     const u64* __restrict__ keys,
                     float* __restrict__ batch_emd) {
    __shared__ float tx[N], ty[N], tz[N];        // 24KB targets
    __shared__ float px[N], py[N], pz[N];        // 24KB preds
    __shared__ u32 holder[N];                    // 8KB
    __shared__ u16 posn[N];                      // 4KB
    __shared__ u16 list16[N * LE];               // 64KB u16 target lists
    __shared__ u16 exq[EXQ];                     // 4KB event ring
    __shared__ u32 talloc;
    __shared__ double dsum[1024];                // 8KB

    const int tid = threadIdx.x;
    const int lane = tid & 63;
    const int b = blockIdx.x;
    const float* pb = pred + (size_t)b * N * 3;
    const float* tb = target + (size_t)b * N * 3;
    const u64* kb = keys + (size_t)b * N * (size_t)K64;

    // ---- setup ----
    for (int idx = tid; idx < 3 * N; idx += 1024) {
        float vp = pb[idx], vt = tb[idx];
        int n = idx / 3, c = idx - 3 * n;
        if (c == 0)      { px[n] = vp; tx[n] = vt; }
        else if (c == 1) { py[n] = vp; ty[n] = vt; }
        else             { pz[n] = vp; tz[n] = vt; }
    }
    for (int j = tid; j < N; j += 1024) { holder[j] = INV; posn[j] = 0; }
    if (tid == 0) talloc = 0;
    for (int idx = tid; idx < N * LE; idx += 1024) {
        const int row = idx >> 4, e = idx & (LE - 1);
        const u64 key = kb[(size_t)row * K64 + e];
        list16[idx] = ((u32)(key >> 32) == INV) ? (u16)0xFFFF
                                                : (u16)((u32)key & (N - 1));
    }
    __syncthreads();

    // ---- stage 1: per-thread batched walks with adoption (atomics) ----
    #pragma unroll
    for (int k = 0; k < 2; ++k) {
        u32 r = (u32)tid + (k ? 1024u : 0u);
        u32 p = 0;
        for (int guard = 0; guard < 200000; ++guard) {
            if (p >= LE) {              // deep walk -> defer to stage 2
                posn[r] = LE;
                const u32 s = atomicAdd(&talloc, 1u);
                exq[s & (EXQ - 1)] = (u16)r;
                break;
            }
            const u32 seg = p & ~7u;
            SEG_PROBE(list16 + (r << 4), seg, r)
            const u32 lv = 0xFFu & ~((1u << (p - seg)) - 1u);
            const u32 evm = (am_ | dm_) & lv;
            if (!evm) { p = seg + 8; continue; }
            const u32 e = (u32)__builtin_ctz(evm);
            if (dm_ & (1u << e)) {      // dead suffix -> overflow row
                posn[r] = 64;
                const u32 s = atomicAdd(&talloc, 1u);
                exq[s & (EXQ - 1)] = (u16)r;
                break;
            }
            const u32 t = SEG_TARGET(e);
            const u32 old = atomicMin(&holder[t], r);
            if (old < r) { p = seg + e + 1; continue; }   // raced: retry
            posn[r] = (u16)(seg + e + 1);                 // held
            if (old == INV) break;                        // chain done
            r = old; p = (u32)posn[r];                    // ADOPT
        }
    }
    __syncthreads();

    // ---- stage 2: ONE wave, exclusive ownership, zero atomics -------------
    if (tid < 64) {
        const u32 TA = talloc;
        for (u32 i = 0; i < TA; ++i) {
            u32 r = (u32)exq[i & (EXQ - 1)];     // uniform
            u32 p = (u32)posn[r];

            for (int cg = 0; cg < 200000; ++cg) {    // cascade with adoption
                u32 nextr = INV;
                bool matched_free = false, resolved = false;

                // A) scalar batched walk over list16 ranks p..15 (uniform;
                //    holder reads are EXACT -- no retries possible)
                while (p < LE) {
                    const u32 seg = p & ~7u;
                    SEG_PROBE(list16 + (r << 4), seg, r)
                    const u32 lv = 0xFFu & ~((1u << (p - seg)) - 1u);
                    const u32 evm = (am_ | dm_) & lv;
                    if (!evm) { p = seg + 8; continue; }
                    const u32 e = (u32)__builtin_ctz(evm);
                    if (dm_ & (1u << e)) { p = 64; break; }  // dead suffix
                    const u32 t = SEG_TARGET(e);
                    const u32 old = SEG_HOLD(e);             // exact
                    if (lane == 0) {
                        holder[t] = r;                       // plain write
                        posn[r] = (u16)(seg + e + 1);
                    }
                    resolved = true;
                    if (old == INV) matched_free = true; else nextr = old;
                    break;
                }

                // B) global top-64 resume: ranks p..63 (per-lane, exact)
                if (!resolved && p < 64) {
                    const u64 key = kb[(size_t)r * K64 + lane];
                    const u32 dv = (u32)(key >> 32);
                    const u32 t = (u32)key & (N - 1);
                    const u32 h = holder[t];
                    const bool cand = ((u32)lane >= p) && (dv != INV) &&
                                      (h > r);
                    const u64 bal = __ballot(cand);
                    if (bal) {
                        const int L = __ffsll((long long)bal) - 1;
                        const u32 tL = (u32)__builtin_amdgcn_readlane((int)t, L);
                        const u32 hL = (u32)__builtin_amdgcn_readlane((int)h, L);
                        if (lane == 0) {
                            holder[tL] = r;
                            posn[r] = (u16)(L + 1);
                        }
                        resolved = true;
                        if (hL == INV) matched_free = true; else nextr = hL;
                    } else {
                        p = 64;                      // continue via scan mode
                        if (lane == 0) posn[r] = 64;
                    }
                }

                // C) single-pass wave scan over {j: holder[j] > r}
                if (!resolved) {
                    const float qx = px[r], qy = py[r], qz = pz[r];
                    u64 best = DEADK;
                    #pragma unroll 4
                    for (int c = 0; c < 32; ++c) {
                        const int j = (c << 6) + lane;
                        if (holder[j] > r) {
                            float dd;
                            DIST(qx, qy, qz, tx, ty, tz, j, dd);
                            const u64 kk = ((u64)__float_as_uint(dd) << 32) |
                                           (u32)j;
                            if (kk < best) best = kk;
                        }
                    }
                    const u64 wm = wave_min64_l63(best);
                    const u32 jw =
                        (u32)__builtin_amdgcn_readlane((int)(u32)wm, 63) & (N - 1);
                    const u32 old = holder[jw];      // uniform broadcast read
                    if (lane == 0) {
                        holder[jw] = r;
                        posn[r] = 64;
                    }
                    if (old == INV) matched_free = true; else nextr = old;
                }

                if (matched_free) break;             // cascade ended
                r = nextr;                           // adopt, continue
                p = (u32)posn[r];
            }
        }
    }
    __syncthreads();

    // ---- final sum over targets (recomputed DIST bit-identical to keys) ---
    double s = 0.0;
    #pragma unroll
    for (int k = 0; k < 2; ++k) {
        const int t = tid + (k ? 1024 : 0);
        const u32 r = holder[t] & (N - 1);
        float dd;
        DIST(px[r], py[r], pz[r], tx, ty, tz, t, dd);
        s += (double)dd;
    }
    dsum[tid] = s;
    __syncthreads();
    for (int st = 512; st >= 1; st >>= 1) {
        if (tid < st) dsum[tid] += dsum[tid + st];
        __syncthreads();
    }
    if (tid == 0) batch_emd[b] = (float)(dsum[0] / N);
}

// ---------------- exact full-scan helper (tiny-ws fallback kernel) --------
__device__ __forceinline__ u64 full_scan_row(
    int lane, float qx, float qy, float qz,
    const float* tx, const float* ty, const float* tz,
    const unsigned char* used) {
  u32 dl = 0xFFFFFFFFu, jl = 0u;
  #pragma unroll 8
  for (int c = 0; c < 32; ++c) {
    const int j = (c << 6) + lane;
    if (!used[j]) {
      float dd;
      DIST(qx, qy, qz, tx, ty, tz, j, dd);
      const u32 db = __float_as_uint(dd);
      if (db < dl) { dl = db; jl = (u32)j; }
    }
  }
  const u32 dmin = wave_umin_bcast(dl);
  const u32 jc = (dl == dmin) ? jl : 0xFFFFFFFFu;
  const u32 jmin = wave_umin_bcast(jc);
  return ((u64)dmin << 32) | jmin;
}

__global__ __launch_bounds__(64, 1)
void emd_greedy_full_kernel(const float* __restrict__ pred,
                            const float* __restrict__ target,
                            float* __restrict__ batch_emd) {
    __shared__ float tx[N], ty[N], tz[N];
    __shared__ float qxs[N], qys[N], qzs[N];
    __shared__ unsigned char used[N];

    const int lane = threadIdx.x;
    const int b = blockIdx.x;
    const float* pb = pred + (size_t)b * N * 3;
    const float* tb = target + (size_t)b * N * 3;

    for (int idx = lane; idx < 3 * N; idx += 64) {
        float vp = pb[idx], vt = tb[idx];
        int n = idx / 3, c = idx - 3 * n;
        if (c == 0)      { qxs[n] = vp; tx[n] = vt; }
        else if (c == 1) { qys[n] = vp; ty[n] = vt; }
        else             { qzs[n] = vp; tz[n] = vt; }
    }
    for (int j = lane; j < N; j += 64) used[j] = 0;

    double sum = 0.0;
    for (int i = 0; i < N; ++i) {
        u64 fs = full_scan_row(lane, qxs[i], qys[i], qzs[i], tx, ty, tz, used);
        sum += (double)__uint_as_float((u32)(fs >> 32));
        if (lane == 0) used[(u32)fs] = 1;
    }
    if (lane == 0) batch_emd[b] = (float)(sum / N);
}

__global__ void emd_mean_kernel(const float* __restrict__ batch_emd,
                                float* __restrict__ out) {
    double s = 0.0;
    for (int b = 0; b < BATCH; ++b) s += (double)batch_emd[b];
    out[0] = (float)(s / BATCH);
}

extern "C" void kernel_launch(void* const* d_in, const int* in_sizes, int n_in,
                              void* d_out, int out_size, void* d_ws, size_t ws_size,
                              hipStream_t stream) {
    const float* pred   = (const float*)d_in[0];
    const float* target = (const float*)d_in[1];
    float* out = (float*)d_out;
    char* wsb = (char*)d_ws;

    const size_t keysz = (size_t)NROWS * K64 * 8;   // 8.4 MB
    if (ws_size >= keysz + 64) {
        u64* keys = (u64*)wsb;
        float* emd = (float*)(wsb + keysz);
        emd_shortsort_kernel<<<NROWS / 4, 256, 0, stream>>>(pred, target, keys);
        emd_da10_kernel<<<BATCH, 1024, 0, stream>>>(pred, target, keys, emd);
        emd_mean_kernel<<<1, 1, 0, stream>>>(emd, out);
    } else {
        float* emd = (float*)wsb;
        emd_greedy_full_kernel<<<BATCH, 64, 0, stream>>>(pred, target, emd);
        emd_mean_kernel<<<1, 1, 0, stream>>>(emd, out);
    }
}

// Round 22
// 588.160 us; speedup vs baseline: 8.5411x; 8.5411x over previous
//
#include <hip/hip_runtime.h>
#include <stdint.h>

#define N 2048
#define BATCH 8
#define NROWS (BATCH * N)   // 16384
#define K64 64              // stored sorted candidates per row
#define LE 16               // LDS list entries per row (ranks 0..15)
#define EXQ 2048            // event ring (>= max pushes)
#define ESLOTS 288          // extension pool slots (ranks 16..63, 48 u16)
#define INV 0xFFFFFFFFu

typedef unsigned long long u64;
typedef unsigned u32;
typedef unsigned short u16;

#define DEADK 0xFFFFFFFFFFFFFFFFull

// ---------------- DPP wave64 reductions -----------------------------------
__device__ __forceinline__ unsigned wave_umin_bcast(unsigned x) {
#define DPP_MIN(ctrl)                                                          \
  {                                                                            \
    unsigned t = (unsigned)__builtin_amdgcn_update_dpp((int)x, (int)x, ctrl,   \
                                                       0xf, 0xf, false);       \
    x = t < x ? t : x;                                                         \
  }
  DPP_MIN(0x111) DPP_MIN(0x112) DPP_MIN(0x114) DPP_MIN(0x118)
  DPP_MIN(0x142) DPP_MIN(0x143)
#undef DPP_MIN
  return (unsigned)__builtin_amdgcn_readlane((int)x, 63);
}

__device__ __forceinline__ unsigned wave_umax_bcast(unsigned x) {
#define DPP_MAX(ctrl)                                                          \
  {                                                                            \
    unsigned t = (unsigned)__builtin_amdgcn_update_dpp((int)x, (int)x, ctrl,   \
                                                       0xf, 0xf, false);       \
    x = t > x ? t : x;                                                         \
  }
  DPP_MAX(0x111) DPP_MAX(0x112) DPP_MAX(0x114) DPP_MAX(0x118)
  DPP_MAX(0x142) DPP_MAX(0x143)
#undef DPP_MAX
  return (unsigned)__builtin_amdgcn_readlane((int)x, 63);
}

#define DPP64_MIN(x, ctrl)                                                     \
  {                                                                            \
    u32 lo_ = (u32)(x), hi_ = (u32)((x) >> 32);                                \
    u32 tlo_ = (u32)__builtin_amdgcn_update_dpp((int)lo_, (int)lo_, (ctrl),    \
                                                0xf, 0xf, false);              \
    u32 thi_ = (u32)__builtin_amdgcn_update_dpp((int)hi_, (int)hi_, (ctrl),    \
                                                0xf, 0xf, false);              \
    u64 t_ = ((u64)thi_ << 32) | tlo_;                                         \
    x = t_ < x ? t_ : x;                                                       \
  }

__device__ __forceinline__ u64 wave_min64_l63(u64 x) {
  DPP64_MIN(x, 0x111) DPP64_MIN(x, 0x112) DPP64_MIN(x, 0x114)
  DPP64_MIN(x, 0x118) DPP64_MIN(x, 0x142) DPP64_MIN(x, 0x143)
  return x;
}

// Exact-order distance: ((dx*dx + dy*dy) + dz*dz), no FMA contraction, sqrtf.
#define DIST(qx, qy, qz, TX, TY, TZ, j, dout)                                  \
  do {                                                                         \
    _Pragma("clang fp contract(off)")                                          \
    float dx_ = (qx) - (TX)[j];                                                \
    float dy_ = (qy) - (TY)[j];                                                \
    float dz_ = (qz) - (TZ)[j];                                                \
    float s_ = dx_ * dx_ + dy_ * dy_ + dz_ * dz_;                              \
    dout = sqrtf(s_);                                                          \
  } while (0)

// ---------------- Phase 1 (FUSED): tau-shortlist -> sorted top-64 ----------
// (verified R19-R21, absmax 0.0)
__global__ __launch_bounds__(256, 1)
void emd_shortsort_kernel(const float* __restrict__ pred,
                          const float* __restrict__ target,
                          u64* __restrict__ keys) {
    __shared__ float tx[N], ty[N], tz[N];        // 24KB
    __shared__ u64 cand[4 * 256];                // 8KB per-wave scratch

    const int b  = blockIdx.x >> 9;
    const int r0 = (blockIdx.x & 511) << 2;
    const float* tb = target + (size_t)b * N * 3;

    for (int idx = threadIdx.x; idx < 3 * N; idx += 256) {
        float v = tb[idx];
        int n = idx / 3, c = idx - 3 * n;
        if (c == 0) tx[n] = v; else if (c == 1) ty[n] = v; else tz[n] = v;
    }
    __syncthreads();

    const int wid = threadIdx.x >> 6, lane = threadIdx.x & 63;
    const int i = r0 + wid;
    const size_t row = (size_t)b * N + i;
    const float* pb = pred + row * 3;
    const float qx = pb[0], qy = pb[1], qz = pb[2];

    float d[32];
    float m = 3.4e38f;
    #pragma unroll
    for (int c = 0; c < 32; ++c) {
        const int j = (c << 6) + lane;
        float dd;
        DIST(qx, qy, qz, tx, ty, tz, j, dd);
        d[c] = dd;
        m = fminf(m, dd);
    }

    unsigned mb = __float_as_uint(m);
    {   // pair-min (xor1 quad_perm): tau = max of 32 min-of-64 -> E[cnt]~130
        unsigned t = (unsigned)__builtin_amdgcn_update_dpp((int)mb, (int)mb,
                                                           0x0B1, 0xf, 0xf, false);
        mb = t < mb ? t : mb;
    }
    const unsigned tau = wave_umax_bcast(mb);
    const float tauf = __uint_as_float(tau);

    u64* cw = cand + wid * 256;
    unsigned base = 0;
    #pragma unroll
    for (int c = 0; c < 32; ++c) {
        const bool p = d[c] <= tauf;
        const u64 bm = __ballot(p);
        if (p) {
            unsigned off = base + (unsigned)__popcll(bm & ((1ull << lane) - 1ull));
            if (off < 256u)
                cw[off] = ((u64)__float_as_uint(d[c]) << 32) |
                          (unsigned)((c << 6) + lane);
        }
        base += (unsigned)__popcll(bm);
    }
    const u32 lim = (base > 256u) ? 0u : base;   // overflow -> all DEADK

    u64 k0 = ((u32)lane       < lim) ? cw[lane      ] : DEADK;
    u64 k1 = ((u32)lane + 64  < lim) ? cw[lane + 64 ] : DEADK;
    u64 k2 = ((u32)lane + 128 < lim) ? cw[lane + 128] : DEADK;
    u64 k3 = ((u32)lane + 192 < lim) ? cw[lane + 192] : DEADK;

#define CSWAP(a, b)                                                            \
  { u64 mn_ = (a) < (b) ? (a) : (b); u64 mx_ = (a) < (b) ? (b) : (a);          \
    (a) = mn_; (b) = mx_; }
    CSWAP(k0, k1) CSWAP(k2, k3) CSWAP(k0, k2) CSWAP(k1, k3) CSWAP(k1, k2)
#undef CSWAP

    u64 mykey = DEADK;
    for (int it = 0; it < K64; ++it) {
        u64 wm = wave_min64_l63(k0);
        u32 wlo = (u32)__builtin_amdgcn_readlane((int)(u32)wm, 63);
        u32 whi = (u32)__builtin_amdgcn_readlane((int)(u32)(wm >> 32), 63);
        if (whi == 0xFFFFFFFFu) break;
        const u64 wkey = ((u64)whi << 32) | wlo;
        mykey = (lane == it) ? wkey : mykey;
        const bool eq = (k0 == wkey);
        k0 = eq ? k1 : k0; k1 = eq ? k2 : k1; k2 = eq ? k3 : k2;
        k3 = eq ? DEADK : k3;
    }
    keys[row * (size_t)K64 + lane] = mykey;
}

// 8-wide batched segment probe: one 16B LDS read + 8 pipelined holder reads;
// builds alive (h>r) / dead (0xFFFF) masks. Named scalars (rule #20).
#define SEG_PROBE(LISTBASE, SEG, R)                                            \
    const uint4 w_ = *(const uint4*)&(LISTBASE)[(SEG)];                        \
    const u32 t0_ = w_.x & 0xFFFFu, t1_ = w_.x >> 16;                          \
    const u32 t2_ = w_.y & 0xFFFFu, t3_ = w_.y >> 16;                          \
    const u32 t4_ = w_.z & 0xFFFFu, t5_ = w_.z >> 16;                          \
    const u32 t6_ = w_.w & 0xFFFFu, t7_ = w_.w >> 16;                          \
    const u32 h0_ = holder[t0_ & (N - 1)], h1_ = holder[t1_ & (N - 1)];        \
    const u32 h2_ = holder[t2_ & (N - 1)], h3_ = holder[t3_ & (N - 1)];        \
    const u32 h4_ = holder[t4_ & (N - 1)], h5_ = holder[t5_ & (N - 1)];        \
    const u32 h6_ = holder[t6_ & (N - 1)], h7_ = holder[t7_ & (N - 1)];        \
    u32 am_ = 0, dm_ = 0;                                                      \
    if (t0_ == 0xFFFFu) dm_ |= 1u;   else if (h0_ > (R)) am_ |= 1u;            \
    if (t1_ == 0xFFFFu) dm_ |= 2u;   else if (h1_ > (R)) am_ |= 2u;            \
    if (t2_ == 0xFFFFu) dm_ |= 4u;   else if (h2_ > (R)) am_ |= 4u;            \
    if (t3_ == 0xFFFFu) dm_ |= 8u;   else if (h3_ > (R)) am_ |= 8u;            \
    if (t4_ == 0xFFFFu) dm_ |= 16u;  else if (h4_ > (R)) am_ |= 16u;           \
    if (t5_ == 0xFFFFu) dm_ |= 32u;  else if (h5_ > (R)) am_ |= 32u;           \
    if (t6_ == 0xFFFFu) dm_ |= 64u;  else if (h6_ > (R)) am_ |= 64u;           \
    if (t7_ == 0xFFFFu) dm_ |= 128u; else if (h7_ > (R)) am_ |= 128u;

#define SEG_TARGET(E)                                                          \
    ((E) < 2 ? ((E) & 1 ? t1_ : t0_)                                           \
             : (E) < 4 ? ((E) & 1 ? t3_ : t2_)                                 \
                       : (E) < 6 ? ((E) & 1 ? t5_ : t4_)                       \
                                 : ((E) & 1 ? t7_ : t6_))

// ---------------- Phase 2: da11 — da9 + one-time LDS extension cache -------
// THEOREM (HW-validated R9-R21, absmax 0.0): greedy row-order matching ==
// unique stable matching == row-proposing DA under ANY proposal order;
// holder[] monotone via atomicMin => rejections permanent; an unmatched row
// is owned by exactly ONE cascade at a time (adoption is immediate).
// R21 (da10, race-free) measured the endgame at ~13M cycles; dominated by
// REPEATED global top-64 reloads (~900cy) and full scans (~2.4kcy) on every
// re-displacement of deep rows. da11: first time a row passes rank 16, its
// ranks 16..63 are copied ONCE into an LDS pool (single-ownership => fill is
// race-free); all later displacements walk LDS (~150cy/hop). Pool overflow ->
// old global path. Scan mode (rank>64) unchanged.
__global__ __launch_bounds__(1024, 1)
void emd_da11_kernel(const float* __restrict__ pred,
                     const float* __restrict__ target,
                     const u64* __restrict__ keys,
                     float* __restrict__ batch_emd) {
    __shared__ float tx[N], ty[N], tz[N];        // 24KB targets
    __shared__ float px[N], py[N], pz[N];        // 24KB preds
    __shared__ u32 holder[N];                    // 8KB
    __shared__ u16 posn[N];                      // 4KB
    __shared__ u16 list16[N * LE];               // 64KB ranks 0..15
    __shared__ u16 extslot[N];                   // 4KB row -> pool slot
    __shared__ u16 extpool[ESLOTS * 48];         // 27KB ranks 16..63
    __shared__ u16 exq[EXQ];                     // 4KB event ring
    __shared__ u32 talloc, head, ealloc;
    __shared__ double dsum[16];

    const int tid = threadIdx.x;
    const int lane = tid & 63;
    const int b = blockIdx.x;
    const float* pb = pred + (size_t)b * N * 3;
    const float* tb = target + (size_t)b * N * 3;
    const u64* kb = keys + (size_t)b * N * (size_t)K64;

    // ---- setup ----
    for (int idx = tid; idx < 3 * N; idx += 1024) {
        float vp = pb[idx], vt = tb[idx];
        int n = idx / 3, c = idx - 3 * n;
        if (c == 0)      { px[n] = vp; tx[n] = vt; }
        else if (c == 1) { py[n] = vp; ty[n] = vt; }
        else             { pz[n] = vp; tz[n] = vt; }
    }
    for (int j = tid; j < N; j += 1024) {
        holder[j] = INV; posn[j] = 0; extslot[j] = 0xFFFF;
    }
    if (tid == 0) { talloc = 0; head = 0; ealloc = 0; }
    for (int idx = tid; idx < N * LE; idx += 1024) {
        const int row = idx >> 4, e = idx & (LE - 1);
        const u64 key = kb[(size_t)row * K64 + e];
        list16[idx] = ((u32)(key >> 32) == INV) ? (u16)0xFFFF
                                                : (u16)((u32)key & (N - 1));
    }
    __syncthreads();

    // ---- stage 1: per-thread batched walks with adoption ----
    #pragma unroll
    for (int k = 0; k < 2; ++k) {
        u32 r = (u32)tid + (k ? 1024u : 0u);
        u32 p = 0;
        for (int guard = 0; guard < 200000; ++guard) {
            if (p >= LE) {              // deep walk -> defer to stage 2
                posn[r] = LE;
                const u32 s = atomicAdd(&talloc, 1u);
                exq[s & (EXQ - 1)] = (u16)r;
                break;
            }
            const u32 seg = p & ~7u;
            SEG_PROBE(list16 + (r << 4), seg, r)
            const u32 lv = 0xFFu & ~((1u << (p - seg)) - 1u);
            const u32 evm = (am_ | dm_) & lv;
            if (!evm) { p = seg + 8; continue; }
            const u32 e = (u32)__builtin_ctz(evm);
            if (dm_ & (1u << e)) {      // dead suffix -> overflow row
                posn[r] = 64;
                const u32 s = atomicAdd(&talloc, 1u);
                exq[s & (EXQ - 1)] = (u16)r;
                break;
            }
            const u32 t = SEG_TARGET(e);
            const u32 old = atomicMin(&holder[t], r);
            if (old < r) { p = seg + e + 1; continue; }   // raced: retry
            posn[r] = (u16)(seg + e + 1);                 // held
            if (old == INV) break;                        // chain done
            r = old; p = (u32)posn[r];                    // ADOPT
        }
    }
    __syncthreads();

    // ---- stage 2: frozen events; LDS-extended walks; wave deep paths ------
    {
        const u32 TA = talloc;          // frozen: stage 2 never pushes
        for (int guard = 0; guard < 20000; ++guard) {
            u32 i = 0;
            if (lane == 0) i = atomicAdd(&head, 1u);
            i = (u32)__builtin_amdgcn_readlane((int)i, 0);
            if (i >= TA) break;
            u32 r = (u32)exq[i & (EXQ - 1)];

            for (int cg = 0; cg < 200000; ++cg) {    // cascade with adoption
                u32 p = (u32)posn[r];                // uniform
                u32 nextr = INV;
                bool matched_free = false, resolved = false;

                // A) batched LDS walk, ranks p..15
                for (int w8 = 0; w8 < 8 && !resolved; ++w8) {
                    if (p >= LE) break;
                    const u32 seg = p & ~7u;
                    SEG_PROBE(list16 + (r << 4), seg, r)
                    const u32 lv = 0xFFu & ~((1u << (p - seg)) - 1u);
                    const u32 evm = (am_ | dm_) & lv;
                    if (!evm) { p = seg + 8; continue; }
                    const u32 e = (u32)__builtin_ctz(evm);
                    if (dm_ & (1u << e)) { p = 64; break; }  // dead suffix
                    const u32 t = SEG_TARGET(e);
                    u32 old = 0;
                    if (lane == 0) old = atomicMin(&holder[t], r);
                    old = (u32)__builtin_amdgcn_readlane((int)old, 0);
                    if (old < r) { p = seg + e + 1; continue; }
                    if (lane == 0) posn[r] = (u16)(seg + e + 1);
                    resolved = true;
                    if (old == INV) matched_free = true; else nextr = old;
                }

                // A2) LDS-extension walk, ranks 16..63 (fill once per row)
                if (!resolved && p >= LE && p < 64) {
                    u32 sl = (u32)extslot[r];
                    if (sl == 0xFFFFu) {       // one-time fill (single owner)
                        u32 ns = 0;
                        if (lane == 0) ns = atomicAdd(&ealloc, 1u);
                        ns = (u32)__builtin_amdgcn_readlane((int)ns, 0);
                        if (ns < (u32)ESLOTS) {
                            if (lane >= 16) {
                                const u64 key = kb[(size_t)r * K64 + lane];
                                extpool[ns * 48 + (lane - 16)] =
                                    ((u32)(key >> 32) == INV)
                                        ? (u16)0xFFFF
                                        : (u16)((u32)key & (N - 1));
                            }
                            if (lane == 0) extslot[r] = (u16)ns;
                            sl = ns;
                        }
                    }
                    if (sl < (u32)ESLOTS) {
                        for (int w8 = 0; w8 < 8 && !resolved; ++w8) {
                            if (p >= 64) break;
                            const u32 ei = p - LE;
                            const u32 seg = ei & ~7u;
                            SEG_PROBE(extpool + sl * 48, seg, r)
                            const u32 lv = 0xFFu & ~((1u << (ei - seg)) - 1u);
                            const u32 evm = (am_ | dm_) & lv;
                            if (!evm) { p = LE + seg + 8; continue; }
                            const u32 e = (u32)__builtin_ctz(evm);
                            if (dm_ & (1u << e)) { p = 64; break; }
                            const u32 t = SEG_TARGET(e);
                            u32 old = 0;
                            if (lane == 0) old = atomicMin(&holder[t], r);
                            old = (u32)__builtin_amdgcn_readlane((int)old, 0);
                            if (old < r) { p = LE + seg + e + 1; continue; }
                            if (lane == 0) posn[r] = (u16)(LE + seg + e + 1);
                            resolved = true;
                            if (old == INV) matched_free = true;
                            else nextr = old;
                        }
                        if (!resolved && lane == 0) posn[r] = (u16)p;
                    } else {
                        // pool exhausted: wave global top-64 resume (old B)
                        const u64 key = kb[(size_t)r * K64 + lane];
                        const u32 dv = (u32)(key >> 32);
                        const u32 t = (u32)key & (N - 1);
                        const bool cand = ((u32)lane >= p) && (dv != INV) &&
                                          (holder[t] > r);
                        u64 bal = __ballot(cand);
                        while (bal) {
                            const int L = __ffsll((long long)bal) - 1;
                            const u32 tL =
                                (u32)__builtin_amdgcn_readlane((int)t, L);
                            u32 old = 0;
                            if (lane == 0) old = atomicMin(&holder[tL], r);
                            old = (u32)__builtin_amdgcn_readlane((int)old, 0);
                            if (old > r) {
                                if (lane == 0) posn[r] = (u16)(L + 1);
                                resolved = true;
                                if (old == INV) matched_free = true;
                                else nextr = old;
                                break;
                            }
                            bal &= ~(1ull << (u32)L);
                        }
                        if (!resolved && lane == 0) posn[r] = 64;
                        if (!resolved) p = 64;
                    }
                }

                // C) wave full scan over {j: holder[j]>r}; DISTs hoisted
                if (!resolved) {
                    const float qx = px[r], qy = py[r], qz = pz[r];
                    u32 dbits[32];
                    #pragma unroll
                    for (int c = 0; c < 32; ++c) {
                        const int j = (c << 6) + lane;
                        float dd;
                        DIST(qx, qy, qz, tx, ty, tz, j, dd);
                        dbits[c] = __float_as_uint(dd);
                    }
                    for (int rty = 0; rty < 100000; ++rty) {
                        u64 best = DEADK;
                        #pragma unroll 8
                        for (int c = 0; c < 32; ++c) {
                            const int j = (c << 6) + lane;
                            if (holder[j] > r) {
                                const u64 kk = ((u64)dbits[c] << 32) | (u32)j;
                                if (kk < best) best = kk;
                            }
                        }
                        const u64 wm = wave_min64_l63(best);
                        const u32 jw =
                            (u32)__builtin_amdgcn_readlane((int)(u32)wm, 63) &
                            (N - 1);
                        u32 old = 0;
                        if (lane == 0) old = atomicMin(&holder[jw], r);
                        old = (u32)__builtin_amdgcn_readlane((int)old, 0);
                        if (old < r) continue;       // lost race: set shrank
                        if (lane == 0) posn[r] = 64;
                        if (old == INV) matched_free = true; else nextr = old;
                        break;
                    }
                }

                if (matched_free) break;             // cascade ended
                r = nextr;                           // adopt, continue
            }
        }
    }
    __syncthreads();

    // ---- final sum over targets (recomputed DIST bit-identical to keys) ---
    double s = 0.0;
    #pragma unroll
    for (int k = 0; k < 2; ++k) {
        const int t = tid + (k ? 1024 : 0);
        const u32 r = holder[t] & (N - 1);
        float dd;
        DIST(px[r], py[r], pz[r], tx, ty, tz, t, dd);
        s += (double)dd;
    }
    #pragma unroll
    for (int m = 32; m >= 1; m >>= 1) s += __shfl_down(s, m, 64);
    if (lane == 0) dsum[tid >> 6] = s;
    __syncthreads();
    if (tid == 0) {
        double tot = 0.0;
        #pragma unroll
        for (int w = 0; w < 16; ++w) tot += dsum[w];
        batch_emd[b] = (float)(tot / N);
    }
}

// ---------------- exact full-scan helper (tiny-ws fallback kernel) --------
__device__ __forceinline__ u64 full_scan_row(
    int lane, float qx, float qy, float qz,
    const float* tx, const float* ty, const float* tz,
    const unsigned char* used) {
  u32 dl = 0xFFFFFFFFu, jl = 0u;
  #pragma unroll 8
  for (int c = 0; c < 32; ++c) {
    const int j = (c << 6) + lane;
    if (!used[j]) {
      float dd;
      DIST(qx, qy, qz, tx, ty, tz, j, dd);
      const u32 db = __float_as_uint(dd);
      if (db < dl) { dl = db; jl = (u32)j; }
    }
  }
  const u32 dmin = wave_umin_bcast(dl);
  const u32 jc = (dl == dmin) ? jl : 0xFFFFFFFFu;
  const u32 jmin = wave_umin_bcast(jc);
  return ((u64)dmin << 32) | jmin;
}

__global__ __launch_bounds__(64, 1)
void emd_greedy_full_kernel(const float* __restrict__ pred,
                            const float* __restrict__ target,
                            float* __restrict__ batch_emd) {
    __shared__ float tx[N], ty[N], tz[N];
    __shared__ float qxs[N], qys[N], qzs[N];
    __shared__ unsigned char used[N];

    const int lane = threadIdx.x;
    const int b = blockIdx.x;
    const float* pb = pred + (size_t)b * N * 3;
    const float* tb = target + (size_t)b * N * 3;

    for (int idx = lane; idx < 3 * N; idx += 64) {
        float vp = pb[idx], vt = tb[idx];
        int n = idx / 3, c = idx - 3 * n;
        if (c == 0)      { qxs[n] = vp; tx[n] = vt; }
        else if (c == 1) { qys[n] = vp; ty[n] = vt; }
        else             { qzs[n] = vp; tz[n] = vt; }
    }
    for (int j = lane; j < N; j += 64) used[j] = 0;

    double sum = 0.0;
    for (int i = 0; i < N; ++i) {
        u64 fs = full_scan_row(lane, qxs[i], qys[i], qzs[i], tx, ty, tz, used);
        sum += (double)__uint_as_float((u32)(fs >> 32));
        if (lane == 0) used[(u32)fs] = 1;
    }
    if (lane == 0) batch_emd[b] = (float)(sum / N);
}

__global__ void emd_mean_kernel(const float* __restrict__ batch_emd,
                                float* __restrict__ out) {
    double s = 0.0;
    for (int b = 0; b < BATCH; ++b) s += (double)batch_emd[b];
    out[0] = (float)(s / BATCH);
}

extern "C" void kernel_launch(void* const* d_in, const int* in_sizes, int n_in,
                              void* d_out, int out_size, void* d_ws, size_t ws_size,
                              hipStream_t stream) {
    const float* pred   = (const float*)d_in[0];
    const float* target = (const float*)d_in[1];
    float* out = (float*)d_out;
    char* wsb = (char*)d_ws;

    const size_t keysz = (size_t)NROWS * K64 * 8;   // 8.4 MB
    if (ws_size >= keysz + 64) {
        u64* keys = (u64*)wsb;
        float* emd = (float*)(wsb + keysz);
        emd_shortsort_kernel<<<NROWS / 4, 256, 0, stream>>>(pred, target, keys);
        emd_da11_kernel<<<BATCH, 1024, 0, stream>>>(pred, target, keys, emd);
        emd_mean_kernel<<<1, 1, 0, stream>>>(emd, out);
    } else {
        float* emd = (float*)wsb;
        emd_greedy_full_kernel<<<BATCH, 64, 0, stream>>>(pred, target, emd);
        emd_mean_kernel<<<1, 1, 0, stream>>>(emd, out);
    }
}

// Round 23
// 526.032 us; speedup vs baseline: 9.5498x; 1.1181x over previous
//
#include <hip/hip_runtime.h>
#include <stdint.h>

#define N 2048
#define BATCH 8
#define NROWS (BATCH * N)   // 16384
#define K64 64              // stored sorted candidates per row
#define LE 16               // LDS list entries per row in DA (ranks 0..15)
#define EXQ 2048            // event ring (>= max pushes)
#define INV 0xFFFFFFFFu

typedef unsigned long long u64;
typedef unsigned u32;
typedef unsigned short u16;

#define DEADK 0xFFFFFFFFFFFFFFFFull

// ---------------- DPP wave64 reductions -----------------------------------
__device__ __forceinline__ unsigned wave_umin_bcast(unsigned x) {
#define DPP_MIN(ctrl)                                                          \
  {                                                                            \
    unsigned t = (unsigned)__builtin_amdgcn_update_dpp((int)x, (int)x, ctrl,   \
                                                       0xf, 0xf, false);       \
    x = t < x ? t : x;                                                         \
  }
  DPP_MIN(0x111) DPP_MIN(0x112) DPP_MIN(0x114) DPP_MIN(0x118)
  DPP_MIN(0x142) DPP_MIN(0x143)
#undef DPP_MIN
  return (unsigned)__builtin_amdgcn_readlane((int)x, 63);
}

__device__ __forceinline__ unsigned wave_umax_bcast(unsigned x) {
#define DPP_MAX(ctrl)                                                          \
  {                                                                            \
    unsigned t = (unsigned)__builtin_amdgcn_update_dpp((int)x, (int)x, ctrl,   \
                                                       0xf, 0xf, false);       \
    x = t > x ? t : x;                                                         \
  }
  DPP_MAX(0x111) DPP_MAX(0x112) DPP_MAX(0x114) DPP_MAX(0x118)
  DPP_MAX(0x142) DPP_MAX(0x143)
#undef DPP_MAX
  return (unsigned)__builtin_amdgcn_readlane((int)x, 63);
}

#define DPP64_MIN(x, ctrl)                                                     \
  {                                                                            \
    u32 lo_ = (u32)(x), hi_ = (u32)((x) >> 32);                                \
    u32 tlo_ = (u32)__builtin_amdgcn_update_dpp((int)lo_, (int)lo_, (ctrl),    \
                                                0xf, 0xf, false);              \
    u32 thi_ = (u32)__builtin_amdgcn_update_dpp((int)hi_, (int)hi_, (ctrl),    \
                                                0xf, 0xf, false);              \
    u64 t_ = ((u64)thi_ << 32) | tlo_;                                         \
    x = t_ < x ? t_ : x;                                                       \
  }

__device__ __forceinline__ u64 wave_min64_l63(u64 x) {
  DPP64_MIN(x, 0x111) DPP64_MIN(x, 0x112) DPP64_MIN(x, 0x114)
  DPP64_MIN(x, 0x118) DPP64_MIN(x, 0x142) DPP64_MIN(x, 0x143)
  return x;
}

// Exact-order distance: ((dx*dx + dy*dy) + dz*dz), no FMA contraction, sqrtf.
#define DIST(qx, qy, qz, TX, TY, TZ, j, dout)                                  \
  do {                                                                         \
    _Pragma("clang fp contract(off)")                                          \
    float dx_ = (qx) - (TX)[j];                                                \
    float dy_ = (qy) - (TY)[j];                                                \
    float dz_ = (qz) - (TZ)[j];                                                \
    float s_ = dx_ * dx_ + dy_ * dy_ + dz_ * dz_;                              \
    dout = sqrtf(s_);                                                          \
  } while (0)

// ---------------- Phase 1 (FUSED): tau-shortlist -> sorted top-64 ----------
// (verified R19-R22, absmax 0.0)
__global__ __launch_bounds__(256, 1)
void emd_shortsort_kernel(const float* __restrict__ pred,
                          const float* __restrict__ target,
                          u64* __restrict__ keys) {
    __shared__ float tx[N], ty[N], tz[N];        // 24KB
    __shared__ u64 cand[4 * 256];                // 8KB per-wave scratch

    const int b  = blockIdx.x >> 9;
    const int r0 = (blockIdx.x & 511) << 2;
    const float* tb = target + (size_t)b * N * 3;

    for (int idx = threadIdx.x; idx < 3 * N; idx += 256) {
        float v = tb[idx];
        int n = idx / 3, c = idx - 3 * n;
        if (c == 0) tx[n] = v; else if (c == 1) ty[n] = v; else tz[n] = v;
    }
    __syncthreads();

    const int wid = threadIdx.x >> 6, lane = threadIdx.x & 63;
    const int i = r0 + wid;
    const size_t row = (size_t)b * N + i;
    const float* pb = pred + row * 3;
    const float qx = pb[0], qy = pb[1], qz = pb[2];

    float d[32];
    float m = 3.4e38f;
    #pragma unroll
    for (int c = 0; c < 32; ++c) {
        const int j = (c << 6) + lane;
        float dd;
        DIST(qx, qy, qz, tx, ty, tz, j, dd);
        d[c] = dd;
        m = fminf(m, dd);
    }

    unsigned mb = __float_as_uint(m);
    {   // pair-min (xor1 quad_perm): tau = max of 32 min-of-64 -> E[cnt]~130
        unsigned t = (unsigned)__builtin_amdgcn_update_dpp((int)mb, (int)mb,
                                                           0x0B1, 0xf, 0xf, false);
        mb = t < mb ? t : mb;
    }
    const unsigned tau = wave_umax_bcast(mb);
    const float tauf = __uint_as_float(tau);

    u64* cw = cand + wid * 256;
    unsigned base = 0;
    #pragma unroll
    for (int c = 0; c < 32; ++c) {
        const bool p = d[c] <= tauf;
        const u64 bm = __ballot(p);
        if (p) {
            unsigned off = base + (unsigned)__popcll(bm & ((1ull << lane) - 1ull));
            if (off < 256u)
                cw[off] = ((u64)__float_as_uint(d[c]) << 32) |
                          (unsigned)((c << 6) + lane);
        }
        base += (unsigned)__popcll(bm);
    }
    const u32 lim = (base > 256u) ? 0u : base;   // overflow -> all DEADK

    u64 k0 = ((u32)lane       < lim) ? cw[lane      ] : DEADK;
    u64 k1 = ((u32)lane + 64  < lim) ? cw[lane + 64 ] : DEADK;
    u64 k2 = ((u32)lane + 128 < lim) ? cw[lane + 128] : DEADK;
    u64 k3 = ((u32)lane + 192 < lim) ? cw[lane + 192] : DEADK;

#define CSWAP(a, b)                                                            \
  { u64 mn_ = (a) < (b) ? (a) : (b); u64 mx_ = (a) < (b) ? (b) : (a);          \
    (a) = mn_; (b) = mx_; }
    CSWAP(k0, k1) CSWAP(k2, k3) CSWAP(k0, k2) CSWAP(k1, k3) CSWAP(k1, k2)
#undef CSWAP

    u64 mykey = DEADK;
    for (int it = 0; it < K64; ++it) {
        u64 wm = wave_min64_l63(k0);
        u32 wlo = (u32)__builtin_amdgcn_readlane((int)(u32)wm, 63);
        u32 whi = (u32)__builtin_amdgcn_readlane((int)(u32)(wm >> 32), 63);
        if (whi == 0xFFFFFFFFu) break;
        const u64 wkey = ((u64)whi << 32) | wlo;
        mykey = (lane == it) ? wkey : mykey;
        const bool eq = (k0 == wkey);
        k0 = eq ? k1 : k0; k1 = eq ? k2 : k1; k2 = eq ? k3 : k2;
        k3 = eq ? DEADK : k3;
    }
    keys[row * (size_t)K64 + lane] = mykey;
}

// 8-wide batched segment probe: one 16B LDS read + 8 pipelined holder reads;
// builds alive (h>r) / dead (0xFFFF) masks. Named scalars (rule #20).
#define SEG_PROBE(LISTBASE, SEG, R)                                            \
    const uint4 w_ = *(const uint4*)&(LISTBASE)[(SEG)];                        \
    const u32 t0_ = w_.x & 0xFFFFu, t1_ = w_.x >> 16;                          \
    const u32 t2_ = w_.y & 0xFFFFu, t3_ = w_.y >> 16;                          \
    const u32 t4_ = w_.z & 0xFFFFu, t5_ = w_.z >> 16;                          \
    const u32 t6_ = w_.w & 0xFFFFu, t7_ = w_.w >> 16;                          \
    const u32 h0_ = holder[t0_ & (N - 1)], h1_ = holder[t1_ & (N - 1)];        \
    const u32 h2_ = holder[t2_ & (N - 1)], h3_ = holder[t3_ & (N - 1)];        \
    const u32 h4_ = holder[t4_ & (N - 1)], h5_ = holder[t5_ & (N - 1)];        \
    const u32 h6_ = holder[t6_ & (N - 1)], h7_ = holder[t7_ & (N - 1)];        \
    u32 am_ = 0, dm_ = 0;                                                      \
    if (t0_ == 0xFFFFu) dm_ |= 1u;   else if (h0_ > (R)) am_ |= 1u;            \
    if (t1_ == 0xFFFFu) dm_ |= 2u;   else if (h1_ > (R)) am_ |= 2u;            \
    if (t2_ == 0xFFFFu) dm_ |= 4u;   else if (h2_ > (R)) am_ |= 4u;            \
    if (t3_ == 0xFFFFu) dm_ |= 8u;   else if (h3_ > (R)) am_ |= 8u;            \
    if (t4_ == 0xFFFFu) dm_ |= 16u;  else if (h4_ > (R)) am_ |= 16u;           \
    if (t5_ == 0xFFFFu) dm_ |= 32u;  else if (h5_ > (R)) am_ |= 32u;           \
    if (t6_ == 0xFFFFu) dm_ |= 64u;  else if (h6_ > (R)) am_ |= 64u;           \
    if (t7_ == 0xFFFFu) dm_ |= 128u; else if (h7_ > (R)) am_ |= 128u;

#define SEG_TARGET(E)                                                          \
    ((E) < 2 ? ((E) & 1 ? t1_ : t0_)                                           \
             : (E) < 4 ? ((E) & 1 ? t3_ : t2_)                                 \
                       : (E) < 6 ? ((E) & 1 ? t5_ : t4_)                       \
                                 : ((E) & 1 ? t7_ : t6_))

// ---------------- Phase 2: da9 — batched-8 walks (best verified, R20) ------
// THEOREM (HW-validated R9-R22, absmax 0.0): greedy row-order matching ==
// unique stable matching == row-proposing DA under ANY proposal order;
// holder[] via atomicMin monotone => rejections permanent; total rank-
// advances are execution-order-invariant. Measured floor: stage-2 endgame =
// ~13M cycles of genuine work (da10 race-free single-wave run), parallelized
// near-linearly across the 16 waves of one CU -> ~440-460us. Six structural
// variants (R12-R22) confirm this is a serialization floor at B=8, not an
// implementation artifact.
__global__ __launch_bounds__(1024, 1)
void emd_da9_kernel(const float* __restrict__ pred,
                    const float* __restrict__ target,
                    const u64* __restrict__ keys,
                    float* __restrict__ batch_emd) {
    __shared__ float tx[N], ty[N], tz[N];        // 24KB targets
    __shared__ float px[N], py[N], pz[N];        // 24KB preds
    __shared__ u32 holder[N];                    // 8KB
    __shared__ u16 posn[N];                      // 4KB
    __shared__ u16 list16[N * LE];               // 64KB u16 target lists
    __shared__ u16 exq[EXQ];                     // 4KB event ring
    __shared__ u32 talloc, head;
    __shared__ double dsum[1024];                // 8KB

    const int tid = threadIdx.x;
    const int lane = tid & 63;
    const int b = blockIdx.x;
    const float* pb = pred + (size_t)b * N * 3;
    const float* tb = target + (size_t)b * N * 3;
    const u64* kb = keys + (size_t)b * N * (size_t)K64;

    // ---- setup ----
    for (int idx = tid; idx < 3 * N; idx += 1024) {
        float vp = pb[idx], vt = tb[idx];
        int n = idx / 3, c = idx - 3 * n;
        if (c == 0)      { px[n] = vp; tx[n] = vt; }
        else if (c == 1) { py[n] = vp; ty[n] = vt; }
        else             { pz[n] = vp; tz[n] = vt; }
    }
    for (int j = tid; j < N; j += 1024) { holder[j] = INV; posn[j] = 0; }
    if (tid == 0) { talloc = 0; head = 0; }
    for (int idx = tid; idx < N * LE; idx += 1024) {
        const int row = idx >> 4, e = idx & (LE - 1);
        const u64 key = kb[(size_t)row * K64 + e];
        list16[idx] = ((u32)(key >> 32) == INV) ? (u16)0xFFFF
                                                : (u16)((u32)key & (N - 1));
    }
    __syncthreads();

    // ---- stage 1: per-thread batched walks with adoption ----
    #pragma unroll
    for (int k = 0; k < 2; ++k) {
        u32 r = (u32)tid + (k ? 1024u : 0u);
        u32 p = 0;
        for (int guard = 0; guard < 200000; ++guard) {
            if (p >= LE) {              // deep walk -> defer to stage 2
                posn[r] = LE;
                const u32 s = atomicAdd(&talloc, 1u);
                exq[s & (EXQ - 1)] = (u16)r;
                break;
            }
            const u32 seg = p & ~7u;
            SEG_PROBE(list16 + (r << 4), seg, r)
            const u32 lv = 0xFFu & ~((1u << (p - seg)) - 1u);
            const u32 evm = (am_ | dm_) & lv;
            if (!evm) { p = seg + 8; continue; }
            const u32 e = (u32)__builtin_ctz(evm);
            if (dm_ & (1u << e)) {      // dead suffix -> overflow row
                posn[r] = 64;
                const u32 s = atomicAdd(&talloc, 1u);
                exq[s & (EXQ - 1)] = (u16)r;
                break;
            }
            const u32 t = SEG_TARGET(e);
            const u32 old = atomicMin(&holder[t], r);
            if (old < r) { p = seg + e + 1; continue; }   // raced: retry
            posn[r] = (u16)(seg + e + 1);                 // held
            if (old == INV) break;                        // chain done
            r = old; p = (u32)posn[r];                    // ADOPT
        }
    }
    __syncthreads();

    // ---- stage 2: frozen event list; batched hops, wave-level deep path ---
    {
        const u32 TA = talloc;          // frozen: stage 2 never pushes
        for (int guard = 0; guard < 20000; ++guard) {
            u32 i = 0;
            if (lane == 0) i = atomicAdd(&head, 1u);
            i = (u32)__builtin_amdgcn_readlane((int)i, 0);
            if (i >= TA) break;
            u32 r = (u32)exq[i & (EXQ - 1)];         // uniform LDS read

            for (int cg = 0; cg < 200000; ++cg) {    // cascade with adoption
                u32 p = (u32)posn[r];                // uniform
                u32 nextr = INV;
                bool matched_free = false, resolved = false;

                // A) batched walk over list16 entries p..15 (wave-uniform)
                for (int w8 = 0; w8 < 24 && !resolved; ++w8) {
                    if (p >= LE) break;
                    const u32 seg = p & ~7u;
                    SEG_PROBE(list16 + (r << 4), seg, r)
                    const u32 lv = 0xFFu & ~((1u << (p - seg)) - 1u);
                    const u32 evm = (am_ | dm_) & lv;
                    if (!evm) { p = seg + 8; continue; }
                    const u32 e = (u32)__builtin_ctz(evm);
                    if (dm_ & (1u << e)) { p = 64; break; }  // dead suffix
                    const u32 t = SEG_TARGET(e);
                    u32 old = 0;
                    if (lane == 0) old = atomicMin(&holder[t], r);
                    old = (u32)__builtin_amdgcn_readlane((int)old, 0);
                    if (old < r) { p = seg + e + 1; continue; }   // raced
                    if (lane == 0) posn[r] = (u16)(seg + e + 1);
                    resolved = true;
                    if (old == INV) matched_free = true; else nextr = old;
                }
                if (!resolved && lane == 0) posn[r] = (u16)p;

                // B) wave-level global top-64 resume: entries p..63
                if (!resolved && p < 64) {
                    const u64 key = kb[(size_t)r * K64 + lane];
                    const u32 dv = (u32)(key >> 32);
                    const u32 t = (u32)key & (N - 1);
                    const bool cand = ((u32)lane >= p) && (dv != INV) &&
                                      (holder[t] > r);
                    u64 bal = __ballot(cand);
                    while (bal) {                    // propose in list order
                        const int L = __ffsll((long long)bal) - 1;
                        const u32 tL = (u32)__builtin_amdgcn_readlane((int)t, L);
                        u32 old = 0;
                        if (lane == 0) old = atomicMin(&holder[tL], r);
                        old = (u32)__builtin_amdgcn_readlane((int)old, 0);
                        if (old > r) {
                            if (lane == 0) posn[r] = (u16)(L + 1);
                            resolved = true;
                            if (old == INV) matched_free = true;
                            else nextr = old;
                            break;
                        }
                        bal &= ~(1ull << (u32)L);    // raced: permanent
                    }
                }

                // C) wave-level full scan over {j: holder[j]>r}; DISTs hoisted
                if (!resolved) {
                    const float qx = px[r], qy = py[r], qz = pz[r];
                    u32 dbits[32];
                    #pragma unroll
                    for (int c = 0; c < 32; ++c) {
                        const int j = (c << 6) + lane;
                        float dd;
                        DIST(qx, qy, qz, tx, ty, tz, j, dd);
                        dbits[c] = __float_as_uint(dd);
                    }
                    for (int rty = 0; rty < 100000; ++rty) {
                        u64 best = DEADK;
                        #pragma unroll 8
                        for (int c = 0; c < 32; ++c) {
                            const int j = (c << 6) + lane;
                            if (holder[j] > r) {
                                const u64 kk = ((u64)dbits[c] << 32) | (u32)j;
                                if (kk < best) best = kk;
                            }
                        }
                        const u64 wm = wave_min64_l63(best);
                        const u32 jw =
                            (u32)__builtin_amdgcn_readlane((int)(u32)wm, 63) &
                            (N - 1);
                        u32 old = 0;
                        if (lane == 0) old = atomicMin(&holder[jw], r);
                        old = (u32)__builtin_amdgcn_readlane((int)old, 0);
                        if (old < r) continue;       // lost race: set shrank
                        if (lane == 0) posn[r] = 64;
                        if (old == INV) matched_free = true; else nextr = old;
                        break;
                    }
                }

                if (matched_free) break;             // cascade ended
                r = nextr;                           // adopt, continue
            }
        }
    }
    __syncthreads();

    // ---- final sum over targets (recomputed DIST bit-identical to keys) ---
    double s = 0.0;
    #pragma unroll
    for (int k = 0; k < 2; ++k) {
        const int t = tid + (k ? 1024 : 0);
        const u32 r = holder[t] & (N - 1);
        float dd;
        DIST(px[r], py[r], pz[r], tx, ty, tz, t, dd);
        s += (double)dd;
    }
    dsum[tid] = s;
    __syncthreads();
    for (int st = 512; st >= 1; st >>= 1) {
        if (tid < st) dsum[tid] += dsum[tid + st];
        __syncthreads();
    }
    if (tid == 0) batch_emd[b] = (float)(dsum[0] / N);
}

// ---------------- exact full-scan helper (tiny-ws fallback kernel) --------
__device__ __forceinline__ u64 full_scan_row(
    int lane, float qx, float qy, float qz,
    const float* tx, const float* ty, const float* tz,
    const unsigned char* used) {
  u32 dl = 0xFFFFFFFFu, jl = 0u;
  #pragma unroll 8
  for (int c = 0; c < 32; ++c) {
    const int j = (c << 6) + lane;
    if (!used[j]) {
      float dd;
      DIST(qx, qy, qz, tx, ty, tz, j, dd);
      const u32 db = __float_as_uint(dd);
      if (db < dl) { dl = db; jl = (u32)j; }
    }
  }
  const u32 dmin = wave_umin_bcast(dl);
  const u32 jc = (dl == dmin) ? jl : 0xFFFFFFFFu;
  const u32 jmin = wave_umin_bcast(jc);
  return ((u64)dmin << 32) | jmin;
}

__global__ __launch_bounds__(64, 1)
void emd_greedy_full_kernel(const float* __restrict__ pred,
                            const float* __restrict__ target,
                            float* __restrict__ batch_emd) {
    __shared__ float tx[N], ty[N], tz[N];
    __shared__ float qxs[N], qys[N], qzs[N];
    __shared__ unsigned char used[N];

    const int lane = threadIdx.x;
    const int b = blockIdx.x;
    const float* pb = pred + (size_t)b * N * 3;
    const float* tb = target + (size_t)b * N * 3;

    for (int idx = lane; idx < 3 * N; idx += 64) {
        float vp = pb[idx], vt = tb[idx];
        int n = idx / 3, c = idx - 3 * n;
        if (c == 0)      { qxs[n] = vp; tx[n] = vt; }
        else if (c == 1) { qys[n] = vp; ty[n] = vt; }
        else             { qzs[n] = vp; tz[n] = vt; }
    }
    for (int j = lane; j < N; j += 64) used[j] = 0;

    double sum = 0.0;
    for (int i = 0; i < N; ++i) {
        u64 fs = full_scan_row(lane, qxs[i], qys[i], qzs[i], tx, ty, tz, used);
        sum += (double)__uint_as_float((u32)(fs >> 32));
        if (lane == 0) used[(u32)fs] = 1;
    }
    if (lane == 0) batch_emd[b] = (float)(sum / N);
}

__global__ void emd_mean_kernel(const float* __restrict__ batch_emd,
                                float* __restrict__ out) {
    double s = 0.0;
    for (int b = 0; b < BATCH; ++b) s += (double)batch_emd[b];
    out[0] = (float)(s / BATCH);
}

extern "C" void kernel_launch(void* const* d_in, const int* in_sizes, int n_in,
                              void* d_out, int out_size, void* d_ws, size_t ws_size,
                              hipStream_t stream) {
    const float* pred   = (const float*)d_in[0];
    const float* target = (const float*)d_in[1];
    float* out = (float*)d_out;
    char* wsb = (char*)d_ws;

    const size_t keysz = (size_t)NROWS * K64 * 8;   // 8.4 MB
    if (ws_size >= keysz + 64) {
        u64* keys = (u64*)wsb;
        float* emd = (float*)(wsb + keysz);
        emd_shortsort_kernel<<<NROWS / 4, 256, 0, stream>>>(pred, target, keys);
        emd_da9_kernel<<<BATCH, 1024, 0, stream>>>(pred, target, keys, emd);
        emd_mean_kernel<<<1, 1, 0, stream>>>(emd, out);
    } else {
        float* emd = (float*)wsb;
        emd_greedy_full_kernel<<<BATCH, 64, 0, stream>>>(pred, target, emd);
        emd_mean_kernel<<<1, 1, 0, stream>>>(emd, out);
    }
}